// Round 16
// baseline (443.582 us; speedup 1.0000x reference)
//
#include <hip/hip_runtime.h>
#include <hip/hip_bf16.h>

#define HDIM 512
#define BDIM 1024
#define DDIM 256
#define MTOT (BDIM * DDIM)

typedef _Float16 half8 __attribute__((ext_vector_type(8)));
typedef _Float16 half4_ __attribute__((ext_vector_type(4)));
typedef float f32x4 __attribute__((ext_vector_type(4)));

__device__ __forceinline__ float ftanh(float x) {
    float e = __expf(2.0f * x);
    float d = e + 1.0f;
    float r;
    asm("v_rcp_f32 %0, %1" : "=v"(r) : "v"(d));
    return 1.0f - 2.0f * r;
}

__device__ __forceinline__ void gl_lds16(const _Float16* src, _Float16* dst) {
    __builtin_amdgcn_global_load_lds((const __attribute__((address_space(1))) void*)src,
                                     (__attribute__((address_space(3))) void*)dst,
                                     16, 0, 0);
}

// K0 (merged): blocks 0..255 = qproj (16 b x 128 g), 256..383 = Wah->W16.
// W16 B-chunk layout: chunk ch = nb*16 + ks is 4096 halves (32 k x 128 cols).
// Granule n: ch=n>>9, r=n&511, j=r>>6, l=r&63:
//   col = (ch>>4)*128 + j*16 + (l&15), k = (ch&15)*32 + (l>>4)*8.
// => linear DMA image; wave's B-frag j read = granules (wc*4+j)*64 + lane,
//    64 consecutive granules -> zero bank conflicts (measured R7+).
__global__ __launch_bounds__(256) void k_prep(const float* __restrict__ h_tilde,
                                              const float* __restrict__ c_t,
                                              const float* __restrict__ Waq,
                                              const float* __restrict__ ba,
                                              const float* __restrict__ Wah,
                                              float* __restrict__ qb,
                                              _Float16* __restrict__ W16) {
    __shared__ float qs[16][1024];
    int t = threadIdx.x;
    if (blockIdx.x >= 256) {
        int n = (blockIdx.x - 256) * 256 + t;     // granule id, 32768 total
        int ch = n >> 9, r = n & 511;
        int j = r >> 6, l = r & 63;
        int col = (ch >> 4) * 128 + j * 16 + (l & 15);
        int k = (ch & 15) * 32 + (l >> 4) * 8;
        const float* src = Wah + (size_t)col * 512 + k;
        float4 v0 = *(const float4*)src;
        float4 v1 = *(const float4*)(src + 4);
        half8 h;
        h[0] = (_Float16)v0.x; h[1] = (_Float16)v0.y; h[2] = (_Float16)v0.z; h[3] = (_Float16)v0.w;
        h[4] = (_Float16)v1.x; h[5] = (_Float16)v1.y; h[6] = (_Float16)v1.z; h[7] = (_Float16)v1.w;
        *(half8*)&W16[(size_t)n * 8] = h;
        return;
    }
    // ---- qproj: block = 16 b x 128 g ----
    int bt = blockIdx.x >> 2, gq = blockIdx.x & 3;
    int b0 = bt * 16;
    #pragma unroll
    for (int i = 0; i < 16; i++) {
        int idx = t + i * 256;
        int row = idx >> 8, k = (idx & 255) * 4;
        float4 v;
        if (k < 512) v = *(const float4*)&h_tilde[(b0 + row) * 512 + k];
        else         v = *(const float4*)&c_t[(b0 + row) * 512 + k - 512];
        *(float4*)&qs[row][k] = v;
    }
    __syncthreads();
    int g = gq * 128 + (t & 127);
    int bh = t >> 7;
    float acc[8] = {0.f, 0.f, 0.f, 0.f, 0.f, 0.f, 0.f, 0.f};
    const float4* wp = (const float4*)&Waq[(size_t)g * 1024];
    #pragma unroll 2
    for (int k4 = 0; k4 < 256; k4++) {
        float4 wv = wp[k4];
        #pragma unroll
        for (int j = 0; j < 8; j++) {
            float4 q = *(const float4*)&qs[bh * 8 + j][k4 * 4];
            acc[j] += q.x * wv.x + q.y * wv.y + q.z * wv.z + q.w * wv.w;
        }
    }
    float bav = ba[g];
    #pragma unroll
    for (int j = 0; j < 8; j++)
        qb[(b0 + bh * 8 + j) * 512 + g] = acc[j] + bav;
}

// K2: m97-style square-tile GEMM + tanh/v fold. Block = 128 rows x 128 cols
// (nb quarter), BK=32, 4 waves 2x2, wave tile 64x64 (acc[4][4] = 64 VGPR).
// A: reg-staged fp32->fp16 cvt, fragment-linear LDS; B: linear global_load_lds
// chunks (conflict-free). Double-buffered, one barrier per K-step.
// XCD-sibling mapping: bx, bx+8, bx+16, bx+24 share mt (same XCD L2 serves
// the X-tile re-reads). nb==0 blocks also emit hist16.
// Epilogue: per-wave 64-col v-dot partials combined ACROSS wc via red[2][128]
// (R15 bug: both wc waves wrote the same logitP slot -> race).
template<int STORE16>
__global__ __launch_bounds__(256, 3) void k_gemm(const float* __restrict__ hist,
                                                 const float* __restrict__ qb,
                                                 const _Float16* __restrict__ W16,
                                                 const float* __restrict__ v_t,
                                                 float* __restrict__ logitP,
                                                 _Float16* __restrict__ hist16) {
    __shared__ _Float16 Ab[2][4096];   // 8 KB each
    __shared__ _Float16 Bb[2][4096];   // 8 KB each
    __shared__ float qbs[128];
    __shared__ float vsh[128];
    __shared__ float red[2][128];

    int t = threadIdx.x;
    int w = t >> 6, lane = t & 63, l15 = lane & 15, l4 = lane >> 4;
    int bx = blockIdx.x;
    int xslot = bx & 7, nb = (bx >> 3) & 3;
    int mt = (bx >> 5) * 8 + xslot;
    size_t m_base = (size_t)mt * 128;
    int b = mt >> 1;                   // 128-row tile within one b
    int wr = w >> 1, wc = w & 1;

    if (t < 128) {
        qbs[t] = qb[b * 512 + nb * 128 + t];
        vsh[t] = v_t[nb * 128 + t];
    }

    const _Float16* wch = W16 + (size_t)nb * 16 * 4096;   // + s*4096 per step

    // A staging: thread t owns row ra = t>>1, k-half koff = (t&1)*16.
    // LDS granule g(r,kp) = (r>>4)*64 + kp*16 + (r&15); this thread writes
    // granules g0, g0+16; frag reads are 64-consecutive granules.
    const float* asrc = hist + (m_base + (t >> 1)) * 512 + (t & 1) * 16;
    const int ga0 = ((t >> 5) * 64 + (t & 1) * 32 + ((t >> 1) & 15)) * 8;
    const int ga1 = ga0 + 128;
    _Float16* h16dst = hist16 + (m_base + (t >> 1)) * 512 + (t & 1) * 16;

    // ---- prologue: DMA B(0), load+cvt+stage A(0) ----
    #pragma unroll
    for (int sg = 0; sg < 2; sg++)
        gl_lds16(wch + ((size_t)(w * 2 + sg) * 64 + lane) * 8,
                 &Bb[0][(w * 2 + sg) * 512]);
    float4 xa0 = *(const float4*)(asrc);
    float4 xa1 = *(const float4*)(asrc + 4);
    float4 xa2 = *(const float4*)(asrc + 8);
    float4 xa3 = *(const float4*)(asrc + 12);
    {
        half8 h0, h1;
        h0[0] = (_Float16)xa0.x; h0[1] = (_Float16)xa0.y; h0[2] = (_Float16)xa0.z; h0[3] = (_Float16)xa0.w;
        h0[4] = (_Float16)xa1.x; h0[5] = (_Float16)xa1.y; h0[6] = (_Float16)xa1.z; h0[7] = (_Float16)xa1.w;
        h1[0] = (_Float16)xa2.x; h1[1] = (_Float16)xa2.y; h1[2] = (_Float16)xa2.z; h1[3] = (_Float16)xa2.w;
        h1[4] = (_Float16)xa3.x; h1[5] = (_Float16)xa3.y; h1[6] = (_Float16)xa3.z; h1[7] = (_Float16)xa3.w;
        *(half8*)&Ab[0][ga0] = h0;
        *(half8*)&Ab[0][ga1] = h1;
        if (STORE16 && nb == 0) {
            *(half8*)(h16dst) = h0;
            *(half8*)(h16dst + 8) = h1;
        }
    }
    __syncthreads();

    f32x4 acc[4][4];
    #pragma unroll
    for (int i = 0; i < 4; i++)
        #pragma unroll
        for (int j = 0; j < 4; j++)
            acc[i][j] = (f32x4){0.f, 0.f, 0.f, 0.f};

    for (int s = 0; s < 16; s++) {
        int cur = s & 1;
        if (s < 15) {
            // issue next B DMA + next A global loads (latency hides under MFMA)
            const _Float16* wc2 = wch + (size_t)(s + 1) * 4096;
            _Float16* bd = Bb[cur ^ 1];
            #pragma unroll
            for (int sg = 0; sg < 2; sg++)
                gl_lds16(wc2 + ((size_t)(w * 2 + sg) * 64 + lane) * 8,
                         &bd[(w * 2 + sg) * 512]);
            const float* pa = asrc + (s + 1) * 32;
            xa0 = *(const float4*)(pa);
            xa1 = *(const float4*)(pa + 4);
            xa2 = *(const float4*)(pa + 8);
            xa3 = *(const float4*)(pa + 12);
        }
        // ---- compute on buf[cur]: 64-consecutive-granule frag reads ----
        const _Float16* ap = Ab[cur];
        const _Float16* bp = Bb[cur];
        half8 afv[4], bfv[4];
        #pragma unroll
        for (int i = 0; i < 4; i++)
            afv[i] = *(const half8*)&ap[((wr * 4 + i) * 64 + lane) * 8];
        #pragma unroll
        for (int j = 0; j < 4; j++)
            bfv[j] = *(const half8*)&bp[((wc * 4 + j) * 64 + lane) * 8];
        __builtin_amdgcn_s_setprio(1);
        #pragma unroll
        for (int i = 0; i < 4; i++)
            #pragma unroll
            for (int j = 0; j < 4; j++)
                acc[i][j] = __builtin_amdgcn_mfma_f32_16x16x32_f16(afv[i], bfv[j], acc[i][j], 0, 0, 0);
        __builtin_amdgcn_s_setprio(0);
        // ---- stage A(s+1) ----
        if (s < 15) {
            half8 h0, h1;
            h0[0] = (_Float16)xa0.x; h0[1] = (_Float16)xa0.y; h0[2] = (_Float16)xa0.z; h0[3] = (_Float16)xa0.w;
            h0[4] = (_Float16)xa1.x; h0[5] = (_Float16)xa1.y; h0[6] = (_Float16)xa1.z; h0[7] = (_Float16)xa1.w;
            h1[0] = (_Float16)xa2.x; h1[1] = (_Float16)xa2.y; h1[2] = (_Float16)xa2.z; h1[3] = (_Float16)xa2.w;
            h1[4] = (_Float16)xa3.x; h1[5] = (_Float16)xa3.y; h1[6] = (_Float16)xa3.z; h1[7] = (_Float16)xa3.w;
            _Float16* ad = Ab[cur ^ 1];
            *(half8*)&ad[ga0] = h0;
            *(half8*)&ad[ga1] = h1;
            if (STORE16 && nb == 0) {
                *(half8*)(h16dst + (s + 1) * 32) = h0;
                *(half8*)(h16dst + (s + 1) * 32 + 8) = h1;
            }
        }
        __syncthreads();   // drains DMA(s+1) + A writes; all waves done with buf[cur]
    }

    // ---- epilogue: tanh + v-dot over this wave's 64 cols -> red[wc] ----
    // C/D map: row = wr*64 + i*16 + l4*4 + r, col = wc*64 + j*16 + l15
    #pragma unroll
    for (int i = 0; i < 4; i++) {
        #pragma unroll
        for (int r = 0; r < 4; r++) {
            float s_ = 0.0f;
            #pragma unroll
            for (int j = 0; j < 4; j++) {
                int col = wc * 64 + j * 16 + l15;
                s_ += ftanh(acc[i][j][r] + qbs[col]) * vsh[col];
            }
            s_ += __shfl_xor(s_, 1, 64);
            s_ += __shfl_xor(s_, 2, 64);
            s_ += __shfl_xor(s_, 4, 64);
            s_ += __shfl_xor(s_, 8, 64);
            if (l15 == 0)
                red[wc][wr * 64 + i * 16 + l4 * 4 + r] = s_;
        }
    }
    __syncthreads();   // both wc halves in red
    if (t < 128)
        logitP[(size_t)nb * MTOT + m_base + t] = red[0][t] + red[1][t];
}

// K3: combine 4 logit partials -> softmax -> e_t (from hist16 if available).
template<int USE16>
__global__ __launch_bounds__(256) void k_softmax_et(const float* __restrict__ hist,
                                                    const _Float16* __restrict__ h16,
                                                    const float* __restrict__ logitP,
                                                    float* __restrict__ out) {
    __shared__ float as_[256];
    __shared__ float wred[4];
    __shared__ float ered[512];
    int b = blockIdx.x, t = threadIdx.x;
    int m0i = b * 256 + t;
    float l = logitP[m0i] + logitP[MTOT + m0i] + logitP[2 * MTOT + m0i] + logitP[3 * MTOT + m0i];
    float m = l;
    m = fmaxf(m, __shfl_xor(m, 1, 64));
    m = fmaxf(m, __shfl_xor(m, 2, 64));
    m = fmaxf(m, __shfl_xor(m, 4, 64));
    m = fmaxf(m, __shfl_xor(m, 8, 64));
    m = fmaxf(m, __shfl_xor(m, 16, 64));
    m = fmaxf(m, __shfl_xor(m, 32, 64));
    if ((t & 63) == 0) wred[t >> 6] = m;
    __syncthreads();
    m = fmaxf(fmaxf(wred[0], wred[1]), fmaxf(wred[2], wred[3]));
    float e = __expf(l - m);
    float s = e;
    s += __shfl_xor(s, 1, 64);
    s += __shfl_xor(s, 2, 64);
    s += __shfl_xor(s, 4, 64);
    s += __shfl_xor(s, 8, 64);
    s += __shfl_xor(s, 16, 64);
    s += __shfl_xor(s, 32, 64);
    __syncthreads();
    if ((t & 63) == 0) wred[t >> 6] = s;
    __syncthreads();
    s = wred[0] + wred[1] + wred[2] + wred[3];
    float a = e / s;
    out[BDIM * HDIM + b * 256 + t] = a;      // alpha
    as_[t] = a;
    __syncthreads();
    int c4 = (t & 127) * 4;
    int dp = t >> 7;
    float e0 = 0.f, e1 = 0.f, e2 = 0.f, e3 = 0.f;
    if (USE16) {
        const _Float16* hb = h16 + (size_t)b * 256 * 512 + c4;
        #pragma unroll 4
        for (int d = dp; d < 256; d += 2) {
            float al = as_[d];
            half4_ h = *(const half4_*)&hb[(size_t)d * 512];
            e0 += al * (float)h[0]; e1 += al * (float)h[1];
            e2 += al * (float)h[2]; e3 += al * (float)h[3];
        }
    } else {
        const float* hb = hist + (size_t)b * 256 * 512 + c4;
        #pragma unroll 4
        for (int d = dp; d < 256; d += 2) {
            float al = as_[d];
            float4 h = *(const float4*)&hb[(size_t)d * 512];
            e0 += al * h.x; e1 += al * h.y; e2 += al * h.z; e3 += al * h.w;
        }
    }
    if (dp) {
        float4 v; v.x = e0; v.y = e1; v.z = e2; v.w = e3;
        *(float4*)&ered[c4] = v;
    }
    __syncthreads();
    if (!dp) {
        float4 p = *(const float4*)&ered[c4];
        float4 r; r.x = e0 + p.x; r.y = e1 + p.y; r.z = e2 + p.z; r.w = e3 + p.w;
        *(float4*)&out[b * 512 + c4] = r;
    }
}

extern "C" void kernel_launch(void* const* d_in, const int* in_sizes, int n_in,
                              void* d_out, int out_size, void* d_ws, size_t ws_size,
                              hipStream_t stream) {
    const float* h_tilde = (const float*)d_in[0];
    const float* c_t     = (const float*)d_in[1];
    const float* hist    = (const float*)d_in[2];
    const float* Waq     = (const float*)d_in[3];
    const float* Wah     = (const float*)d_in[4];
    const float* ba      = (const float*)d_in[5];
    const float* v_t     = (const float*)d_in[6];
    float* out = (float*)d_out;

    char* ws = (char*)d_ws;
    float*    qb     = (float*)ws;                                // 2 MB
    _Float16* W16    = (_Float16*)(ws + (2u << 20));              // 512 KB
    float*    logitP = (float*)(ws + (3u << 20));                 // 4 MB
    _Float16* hist16 = (_Float16*)(ws + (8u << 20));              // 268 MB
    bool use16 = ws_size >= (size_t)(8u << 20) + (size_t)MTOT * 512 * 2;

    k_prep<<<384, 256, 0, stream>>>(h_tilde, c_t, Waq, ba, Wah, qb, W16);
    if (use16) {
        k_gemm<1><<<8192, 256, 0, stream>>>(hist, qb, W16, v_t, logitP, hist16);
        k_softmax_et<1><<<1024, 256, 0, stream>>>(hist, hist16, logitP, out);
    } else {
        k_gemm<0><<<8192, 256, 0, stream>>>(hist, qb, W16, v_t, logitP, hist16);
        k_softmax_et<0><<<1024, 256, 0, stream>>>(hist, hist16, logitP, out);
    }
}

// Round 17
// 357.562 us; speedup vs baseline: 1.2406x; 1.2406x over previous
//
#include <hip/hip_runtime.h>
#include <hip/hip_bf16.h>

#define HDIM 512
#define BDIM 1024
#define DDIM 256
#define MTOT (BDIM * DDIM)

typedef _Float16 half8 __attribute__((ext_vector_type(8)));
typedef float f32x16 __attribute__((ext_vector_type(16)));

__device__ __forceinline__ float ftanh(float x) {
    float e = __expf(2.0f * x);
    float d = e + 1.0f;
    float r;
    asm("v_rcp_f32 %0, %1" : "=v"(r) : "v"(d));
    return 1.0f - 2.0f * r;
}

__device__ __forceinline__ void gl_lds16(const _Float16* src, _Float16* dst) {
    __builtin_amdgcn_global_load_lds((const __attribute__((address_space(1))) void*)src,
                                     (__attribute__((address_space(3))) void*)dst,
                                     16, 0, 0);
}

// K0 (merged): blocks 0..255 = qproj (16 b x 128 g), 256..383 = Wah->W16.
// W16 PHASE-major for 32x32x16 MFMA: 64 phases of 4096 halves.
// Phase p = (c, kq): c = p>>2 (32-col group), kq = p&3 (128-k quarter).
// Granule g = i*64 + l within phase (i = k-slice 0..7, l = lane):
//   holds Wah[c*32 + (l&31)][kq*128 + i*16 + (l>>5)*8 .. +8].
// => linear DMA image; B-frag read (slice i) = granules i*64 + lane:
//    64 consecutive granules per wave -> zero bank conflicts (measured R7+).
__global__ __launch_bounds__(256) void k_prep(const float* __restrict__ h_tilde,
                                              const float* __restrict__ c_t,
                                              const float* __restrict__ Waq,
                                              const float* __restrict__ ba,
                                              const float* __restrict__ Wah,
                                              float* __restrict__ qb,
                                              _Float16* __restrict__ W16) {
    __shared__ float qs[16][1024];
    int t = threadIdx.x;
    if (blockIdx.x >= 256) {
        int n = (blockIdx.x - 256) * 256 + t;     // granule id, 32768 total
        int p = n >> 9, g = n & 511;
        int i = g >> 6, l = g & 63;
        int col = (p >> 2) * 32 + (l & 31);
        int k = (p & 3) * 128 + i * 16 + (l >> 5) * 8;
        const float* src = Wah + (size_t)col * 512 + k;
        float4 v0 = *(const float4*)src;
        float4 v1 = *(const float4*)(src + 4);
        half8 h;
        h[0] = (_Float16)v0.x; h[1] = (_Float16)v0.y; h[2] = (_Float16)v0.z; h[3] = (_Float16)v0.w;
        h[4] = (_Float16)v1.x; h[5] = (_Float16)v1.y; h[6] = (_Float16)v1.z; h[7] = (_Float16)v1.w;
        *(half8*)&W16[(size_t)n * 8] = h;
        return;
    }
    // ---- qproj: block = 16 b x 128 g ----
    int bt = blockIdx.x >> 2, gq = blockIdx.x & 3;
    int b0 = bt * 16;
    #pragma unroll
    for (int i = 0; i < 16; i++) {
        int idx = t + i * 256;
        int row = idx >> 8, k = (idx & 255) * 4;
        float4 v;
        if (k < 512) v = *(const float4*)&h_tilde[(b0 + row) * 512 + k];
        else         v = *(const float4*)&c_t[(b0 + row) * 512 + k - 512];
        *(float4*)&qs[row][k] = v;
    }
    __syncthreads();
    int g = gq * 128 + (t & 127);
    int bh = t >> 7;
    float acc[8] = {0.f, 0.f, 0.f, 0.f, 0.f, 0.f, 0.f, 0.f};
    const float4* wp = (const float4*)&Waq[(size_t)g * 1024];
    #pragma unroll 2
    for (int k4 = 0; k4 < 256; k4++) {
        float4 wv = wp[k4];
        #pragma unroll
        for (int j = 0; j < 8; j++) {
            float4 q = *(const float4*)&qs[bh * 8 + j][k4 * 4];
            acc[j] += q.x * wv.x + q.y * wv.y + q.z * wv.z + q.w * wv.w;
        }
    }
    float bav = ba[g];
    #pragma unroll
    for (int j = 0; j < 8; j++)
        qb[(b0 + bh * 8 + j) * 512 + g] = acc[j] + bav;
}

// K2: 128 rows/block, 4 waves x 32 rows (32x32x16 MFMA: one 16B B-frag read
// serves 32 rows x 32 cols -> LDS reads HALVED vs R14). afr[32] (static
// indices), counted-vmcnt 4-buffer pipeline (R14 machinery verbatim),
// fused flash partial softmax + partial e_t. 2 blocks/CU (2 waves/SIMD).
__global__ __launch_bounds__(256, 2) void k_logits(const float* __restrict__ hist,
                                                   const float* __restrict__ qb,
                                                   const _Float16* __restrict__ W16,
                                                   const float* __restrict__ v_t,
                                                   float* __restrict__ logits,
                                                   float* __restrict__ eparts,
                                                   float* __restrict__ ms) {
    __shared__ _Float16 Wb[4][4096];   // 8 KB each; reused as e_t scratch after loop
    __shared__ float qbs[512];
    __shared__ float vsh[512];
    __shared__ float lsh[128];
    __shared__ float wredM[2];
    __shared__ float wredS[2];

    int t = threadIdx.x;
    int w = t >> 6, lane = t & 63, l31 = lane & 31, lh = lane >> 5;
    int bx = blockIdx.x;
    size_t m_base = (size_t)bx * 128;
    int b = bx >> 1;
    int offp = ((bx >> 1) & 7) * 8;    // multiple of 4 -> kq phase parity kept

    qbs[t] = qb[b * 512 + t];
    qbs[t + 256] = qb[b * 512 + 256 + t];
    vsh[t] = v_t[t];
    vsh[t + 256] = v_t[256 + t];

    // prologue: issue DMA for phases 0,1 (2 ops each per wave)
    #pragma unroll
    for (int pp = 0; pp < 2; pp++) {
        const _Float16* wc = W16 + (size_t)((pp + offp) & 63) * 4096;
        #pragma unroll
        for (int sg = 0; sg < 2; sg++)
            gl_lds16(wc + ((size_t)(w * 2 + sg) * 64 + lane) * 8,
                     &Wb[pp][(w * 2 + sg) * 512]);
    }

    // X-load, depth-4 ring (static slots):
    // afr[s] = hist[m_base + w*32 + l31][s*16 + lh*8 .. +8] as fp16
    half8 afr[32];
    const float* xb = hist + (m_base + w * 32 + l31) * 512 + lh * 8;
    {
        float4 xr0[4], xr1[4];
        #pragma unroll
        for (int u = 0; u < 4; u++) {
            xr0[u] = *(const float4*)(xb + u * 16);
            xr1[u] = *(const float4*)(xb + u * 16 + 4);
        }
        #pragma unroll
        for (int kb = 0; kb < 32; kb++) {
            const int slot = kb & 3;
            float4 v0 = xr0[slot];
            float4 v1 = xr1[slot];
            if (kb + 4 < 32) {
                xr0[slot] = *(const float4*)(xb + (kb + 4) * 16);
                xr1[slot] = *(const float4*)(xb + (kb + 4) * 16 + 4);
            }
            half8 h;
            h[0] = (_Float16)v0.x; h[1] = (_Float16)v0.y; h[2] = (_Float16)v0.z; h[3] = (_Float16)v0.w;
            h[4] = (_Float16)v1.x; h[5] = (_Float16)v1.y; h[6] = (_Float16)v1.z; h[7] = (_Float16)v1.w;
            afr[kb] = h;
        }
    }

    float S[16];
    #pragma unroll
    for (int r = 0; r < 16; r++) S[r] = 0.f;
    f32x16 tac;

    asm volatile("s_waitcnt lgkmcnt(0)" ::: "memory");  // own qbs/vsh ds_writes

    // KQ literal (0..3) -> afr index static. p_ runtime: address math only.
#define PHASE_BODY(P, VMS, ISSUE, KQ)                                          \
    {                                                                          \
        const int p_ = (P);                                                    \
        asm volatile("s_waitcnt vmcnt(" VMS ")" ::: "memory");                 \
        __builtin_amdgcn_s_barrier();                                          \
        if (ISSUE) {                                                           \
            const _Float16* wc_ = W16 + (size_t)((p_ + 2 + offp) & 63) * 4096; \
            _Float16* wd_ = Wb[(p_ + 2) & 3];                                  \
            _Pragma("unroll")                                                  \
            for (int sg_ = 0; sg_ < 2; sg_++)                                  \
                gl_lds16(wc_ + ((size_t)(w * 2 + sg_) * 64 + lane) * 8,        \
                         &wd_[(w * 2 + sg_) * 512]);                           \
        }                                                                      \
        const int cc_ = ((p_ + offp) & 63) >> 2;                               \
        const _Float16* bufp_ = &Wb[p_ & 3][lane * 8];                         \
        if ((KQ) == 0) {                                                       \
            _Pragma("unroll")                                                  \
            for (int r_ = 0; r_ < 16; r_++) tac[r_] = 0.f;                     \
        }                                                                      \
        __builtin_amdgcn_s_setprio(1);                                         \
        _Pragma("unroll")                                                      \
        for (int i_ = 0; i_ < 8; i_++) {                                       \
            half8 bf = *(const half8*)(bufp_ + i_ * 512);                      \
            tac = __builtin_amdgcn_mfma_f32_32x32x16_f16(afr[(KQ) * 8 + i_], bf, tac, 0, 0, 0); \
        }                                                                      \
        __builtin_amdgcn_s_setprio(0);                                         \
        if ((KQ) == 3) {                                                       \
            float qv = qbs[cc_ * 32 + l31];                                    \
            float vv = vsh[cc_ * 32 + l31];                                    \
            _Pragma("unroll")                                                  \
            for (int r_ = 0; r_ < 16; r_++)                                    \
                S[r_] += ftanh(tac[r_] + qv) * vv;                             \
        }                                                                      \
    }

    for (int q = 0; q < 15; q++) {
        PHASE_BODY(4 * q,     "2", true, 0)
        PHASE_BODY(4 * q + 1, "2", true, 1)
        PHASE_BODY(4 * q + 2, "2", true, 2)
        PHASE_BODY(4 * q + 3, "2", true, 3)
    }
    PHASE_BODY(60, "2", true,  0)
    PHASE_BODY(61, "2", true,  1)
    PHASE_BODY(62, "2", false, 2)
    PHASE_BODY(63, "0", false, 3)
#undef PHASE_BODY

    // ---- logits: reduce S over l31 (cols); C/D row = (r&3)+8*(r>>2)+4*lh ----
    #pragma unroll
    for (int r = 0; r < 16; r++) {
        float s = S[r];
        s += __shfl_xor(s, 1, 64);
        s += __shfl_xor(s, 2, 64);
        s += __shfl_xor(s, 4, 64);
        s += __shfl_xor(s, 8, 64);
        s += __shfl_xor(s, 16, 64);
        if (l31 == 0) {
            int row = w * 32 + (r & 3) + 8 * (r >> 2) + 4 * lh;
            logits[m_base + row] = s;
            lsh[row] = s;
        }
    }
    __syncthreads();   // lsh complete; all waves past Wb reads

    // ---- block-local softmax stats over the 128 rows ----
    float lv = lsh[t & 127];           // waves 0,1 cover 0..127; 2,3 mirror
    float mb = lv;
    mb = fmaxf(mb, __shfl_xor(mb, 1, 64));
    mb = fmaxf(mb, __shfl_xor(mb, 2, 64));
    mb = fmaxf(mb, __shfl_xor(mb, 4, 64));
    mb = fmaxf(mb, __shfl_xor(mb, 8, 64));
    mb = fmaxf(mb, __shfl_xor(mb, 16, 64));
    mb = fmaxf(mb, __shfl_xor(mb, 32, 64));
    if (lane == 0 && w < 2) wredM[w] = mb;
    __syncthreads();
    mb = fmaxf(wredM[0], wredM[1]);
    float e = __expf(lv - mb);
    float sb = e;
    sb += __shfl_xor(sb, 1, 64);
    sb += __shfl_xor(sb, 2, 64);
    sb += __shfl_xor(sb, 4, 64);
    sb += __shfl_xor(sb, 8, 64);
    sb += __shfl_xor(sb, 16, 64);
    sb += __shfl_xor(sb, 32, 64);
    if (lane == 0 && w < 2) wredS[w] = sb;
    __syncthreads();
    sb = wredS[0] + wredS[1];

    // ---- partial e_t from afr: lane holds row w*32 + l31, k-half lh ----
    float coef = __expf(lsh[w * 32 + l31] - mb);
    float* ews = (float*)Wb;           // reuse 8 KB of Wb as [4][512] scratch
    #pragma unroll
    for (int kb = 0; kb < 32; kb++) {
        float ep[8];
        half8 x = afr[kb];
        #pragma unroll
        for (int e2 = 0; e2 < 8; e2++) ep[e2] = coef * (float)x[e2];
        #pragma unroll
        for (int e2 = 0; e2 < 8; e2++) {
            ep[e2] += __shfl_xor(ep[e2], 1, 64);
            ep[e2] += __shfl_xor(ep[e2], 2, 64);
            ep[e2] += __shfl_xor(ep[e2], 4, 64);
            ep[e2] += __shfl_xor(ep[e2], 8, 64);
            ep[e2] += __shfl_xor(ep[e2], 16, 64);
        }
        if (l31 == 0) {
            #pragma unroll
            for (int e2 = 0; e2 < 8; e2++)
                ews[w * 512 + kb * 16 + lh * 8 + e2] = ep[e2];
        }
    }
    __syncthreads();
    float v0 = ews[t] + ews[512 + t] + ews[1024 + t] + ews[1536 + t];
    float v1 = ews[256 + t] + ews[768 + t] + ews[1280 + t] + ews[1792 + t];
    eparts[(size_t)bx * 512 + t] = v0;
    eparts[(size_t)bx * 512 + 256 + t] = v1;
    if (t == 0) { ms[bx * 2] = mb; ms[bx * 2 + 1] = sb; }
}

// K3: combine 2 block-partials per b (exact flash-combine) -> alpha + e_t.
__global__ __launch_bounds__(256) void k_comb(const float* __restrict__ logits,
                                              const float* __restrict__ eparts,
                                              const float* __restrict__ ms,
                                              float* __restrict__ out) {
    int b = blockIdx.x, t = threadIdx.x;
    float m0 = ms[4 * b], s0 = ms[4 * b + 1];
    float m1 = ms[4 * b + 2], s1 = ms[4 * b + 3];
    float m = fmaxf(m0, m1);
    float w0 = __expf(m0 - m), w1 = __expf(m1 - m);
    float Sb = w0 * s0 + w1 * s1;
    float l = logits[b * 256 + t];
    out[BDIM * HDIM + b * 256 + t] = __expf(l - m) / Sb;   // alpha
    const float* ep = eparts + (size_t)(2 * b) * 512;
    float a0 = w0 * ep[t] + w1 * ep[512 + t];
    float a1 = w0 * ep[256 + t] + w1 * ep[768 + t];
    out[b * 512 + t] = a0 / Sb;                            // e_t
    out[b * 512 + 256 + t] = a1 / Sb;
}

extern "C" void kernel_launch(void* const* d_in, const int* in_sizes, int n_in,
                              void* d_out, int out_size, void* d_ws, size_t ws_size,
                              hipStream_t stream) {
    const float* h_tilde = (const float*)d_in[0];
    const float* c_t     = (const float*)d_in[1];
    const float* hist    = (const float*)d_in[2];
    const float* Waq     = (const float*)d_in[3];
    const float* Wah     = (const float*)d_in[4];
    const float* ba      = (const float*)d_in[5];
    const float* v_t     = (const float*)d_in[6];
    float* out = (float*)d_out;

    char* ws = (char*)d_ws;
    float*    qb     = (float*)ws;                                // 2 MB
    _Float16* W16    = (_Float16*)(ws + (2u << 20));              // 512 KB
    float*    logits = (float*)(ws + (3u << 20));                 // 1 MB
    float*    eparts = (float*)(ws + (4u << 20));                 // 4 MB
    float*    ms     = (float*)(ws + (8u << 20));                 // 16 KB

    k_prep<<<384, 256, 0, stream>>>(h_tilde, c_t, Waq, ba, Wah, qb, W16);
    k_logits<<<2048, 256, 0, stream>>>(hist, qb, W16, v_t, logits, eparts, ms);
    k_comb<<<1024, 256, 0, stream>>>(logits, eparts, ms, out);
}

// Round 21
// 349.800 us; speedup vs baseline: 1.2681x; 1.0222x over previous
//
#include <hip/hip_runtime.h>
#include <hip/hip_bf16.h>

#define HDIM 512
#define BDIM 1024
#define DDIM 256
#define MTOT (BDIM * DDIM)

typedef _Float16 half8 __attribute__((ext_vector_type(8)));
typedef float f32x4 __attribute__((ext_vector_type(4)));

__device__ __forceinline__ float ftanh(float x) {
    float e = __expf(2.0f * x);
    float d = e + 1.0f;
    float r;
    asm("v_rcp_f32 %0, %1" : "=v"(r) : "v"(d));
    return 1.0f - 2.0f * r;
}

__device__ __forceinline__ void gl_lds16(const _Float16* src, _Float16* dst) {
    __builtin_amdgcn_global_load_lds((const __attribute__((address_space(1))) void*)src,
                                     (__attribute__((address_space(3))) void*)dst,
                                     16, 0, 0);
}

// K0 (merged): blocks 0..255 = qproj (16 b x 128 g tiles), 256..383 = convert.
// W16 PHASE-major: 64 phases of 4096 halves (16 cols x 256 k). Within phase
// p=(c,kh): granule kb*64 + kp*16 + g holds Wah[c*16+g][kh*256 + kb*32 + kp*8].
// B-frag for lane l = granule kb*64 + l -> 1024 consecutive bytes per wave
// (measured 0 bank conflicts).
__global__ __launch_bounds__(256) void k_prep(const float* __restrict__ h_tilde,
                                              const float* __restrict__ c_t,
                                              const float* __restrict__ Waq,
                                              const float* __restrict__ ba,
                                              const float* __restrict__ Wah,
                                              float* __restrict__ qb,
                                              _Float16* __restrict__ W16) {
    __shared__ float qs[16][1024];
    int t = threadIdx.x;
    if (blockIdx.x >= 256) {
        int n = (blockIdx.x - 256) * 256 + t;     // granule id, 32768 total
        int p = n >> 9, r = n & 511;
        int kb = r >> 6, kp = (r >> 4) & 3, g = r & 15;
        int c = p >> 1, kh = p & 1;
        const float* src = Wah + (size_t)(c * 16 + g) * 512 + kh * 256 + kb * 32 + kp * 8;
        float4 v0 = *(const float4*)src;
        float4 v1 = *(const float4*)(src + 4);
        half8 h;
        h[0] = (_Float16)v0.x; h[1] = (_Float16)v0.y; h[2] = (_Float16)v0.z; h[3] = (_Float16)v0.w;
        h[4] = (_Float16)v1.x; h[5] = (_Float16)v1.y; h[6] = (_Float16)v1.z; h[7] = (_Float16)v1.w;
        *(half8*)&W16[(size_t)n * 8] = h;
        return;
    }
    // ---- qproj: block = 16 b x 128 g ----
    int bt = blockIdx.x >> 2, gq = blockIdx.x & 3;
    int b0 = bt * 16;
    #pragma unroll
    for (int i = 0; i < 16; i++) {
        int idx = t + i * 256;
        int row = idx >> 8, k = (idx & 255) * 4;
        float4 v;
        if (k < 512) v = *(const float4*)&h_tilde[(b0 + row) * 512 + k];
        else         v = *(const float4*)&c_t[(b0 + row) * 512 + k - 512];
        *(float4*)&qs[row][k] = v;
    }
    __syncthreads();
    int g = gq * 128 + (t & 127);
    int bh = t >> 7;
    float acc[8] = {0.f, 0.f, 0.f, 0.f, 0.f, 0.f, 0.f, 0.f};
    const float4* wp = (const float4*)&Waq[(size_t)g * 1024];
    #pragma unroll 2
    for (int k4 = 0; k4 < 256; k4++) {
        float4 wv = wp[k4];
        #pragma unroll
        for (int j = 0; j < 8; j++) {
            float4 q = *(const float4*)&qs[bh * 8 + j][k4 * 4];
            acc[j] += q.x * wv.x + q.y * wv.y + q.z * wv.z + q.w * wv.w;
        }
    }
    float bav = ba[g];
    #pragma unroll
    for (int j = 0; j < 8; j++)
        qb[(b0 + bh * 8 + j) * 512 + g] = acc[j] + bav;
}

// K2: 64 rows x full N, 4 waves, afr[16] (64 AGPR, STATIC indices only),
// 4 blocks/CU, fused flash partial softmax + partial e_t. Counted-vmcnt
// pipeline: 64 phases of 8 KB through 4 buffers; body(p): vmcnt(2) [buf p
// complete, p+1 in flight] -> s_barrier -> issue p+2 -> 8 ds_read + 8 MFMA
// -> fold on odd phase. Loop emitted as 31 pairs with literal KH=0/1 so all
// afr[] indices are compile-time (rule #20: runtime-indexed reg arrays spill).
__global__ __launch_bounds__(256, 4) void k_logits(const float* __restrict__ hist,
                                                   const float* __restrict__ qb,
                                                   const _Float16* __restrict__ W16,
                                                   const float* __restrict__ v_t,
                                                   float* __restrict__ logits,
                                                   float* __restrict__ eparts,
                                                   float* __restrict__ ms) {
    __shared__ _Float16 Wb[4][4096];   // 8 KB each; reused as e_t scratch after loop
    __shared__ float qbs[512];
    __shared__ float vsh[512];
    __shared__ float lsh[64];

    int t = threadIdx.x;
    int w = t >> 6, lane = t & 63, l15 = lane & 15, l4 = lane >> 4;
    int bx = blockIdx.x;
    size_t m_base = (size_t)bx * 64;
    int b = bx >> 2;
    int offp = ((bx >> 3) & 3) * 16;   // EVEN stagger -> kh parity preserved

    qbs[t] = qb[b * 512 + t];
    qbs[t + 256] = qb[b * 512 + 256 + t];
    vsh[t] = v_t[t];
    vsh[t + 256] = v_t[256 + t];

    // prologue: issue DMA for phases 0,1 (2 ops each per wave)
    #pragma unroll
    for (int pp = 0; pp < 2; pp++) {
        const _Float16* wc = W16 + (size_t)((pp + offp) & 63) * 4096;
        #pragma unroll
        for (int sg = 0; sg < 2; sg++)
            gl_lds16(wc + ((size_t)(w * 2 + sg) * 64 + lane) * 8,
                     &Wb[pp][(w * 2 + sg) * 512]);
    }

    // X-load, depth-4 ring (static slots): afr[kb] = X[w*16+l15][kb*32+l4*8..+8]
    half8 afr[16];
    const float* xb = hist + (m_base + w * 16 + l15) * 512 + l4 * 8;
    {
        float4 xr0[4], xr1[4];
        #pragma unroll
        for (int u = 0; u < 4; u++) {
            xr0[u] = *(const float4*)(xb + u * 32);
            xr1[u] = *(const float4*)(xb + u * 32 + 4);
        }
        #pragma unroll
        for (int kb = 0; kb < 16; kb++) {
            const int slot = kb & 3;
            float4 v0 = xr0[slot];
            float4 v1 = xr1[slot];
            if (kb + 4 < 16) {
                xr0[slot] = *(const float4*)(xb + (kb + 4) * 32);
                xr1[slot] = *(const float4*)(xb + (kb + 4) * 32 + 4);
            }
            half8 h;
            h[0] = (_Float16)v0.x; h[1] = (_Float16)v0.y; h[2] = (_Float16)v0.z; h[3] = (_Float16)v0.w;
            h[4] = (_Float16)v1.x; h[5] = (_Float16)v1.y; h[6] = (_Float16)v1.z; h[7] = (_Float16)v1.w;
            afr[kb] = h;
        }
    }

    float S[4] = {0.f, 0.f, 0.f, 0.f};
    f32x4 tac = (f32x4){0.f, 0.f, 0.f, 0.f};

    asm volatile("s_waitcnt lgkmcnt(0)" ::: "memory");  // own qbs/vsh ds_writes

    // KH is a LITERAL (0/1) -> afr index static. p_ runtime: address math only.
#define PHASE_BODY(P, VMS, ISSUE, KH)                                          \
    {                                                                          \
        const int p_ = (P);                                                    \
        asm volatile("s_waitcnt vmcnt(" VMS ")" ::: "memory");                 \
        __builtin_amdgcn_s_barrier();                                          \
        if (ISSUE) {                                                           \
            const _Float16* wc_ = W16 + (size_t)((p_ + 2 + offp) & 63) * 4096; \
            _Float16* wd_ = Wb[(p_ + 2) & 3];                                  \
            _Pragma("unroll")                                                  \
            for (int sg_ = 0; sg_ < 2; sg_++)                                  \
                gl_lds16(wc_ + ((size_t)(w * 2 + sg_) * 64 + lane) * 8,        \
                         &wd_[(w * 2 + sg_) * 512]);                           \
        }                                                                      \
        const int cc_ = ((p_ + offp) & 63) >> 1;                               \
        const _Float16* bufp_ = &Wb[p_ & 3][lane * 8];                         \
        if ((KH) == 0) tac = (f32x4){0.f, 0.f, 0.f, 0.f};                      \
        __builtin_amdgcn_s_setprio(1);                                         \
        _Pragma("unroll")                                                      \
        for (int kb_ = 0; kb_ < 8; kb_++) {                                    \
            half8 bf = *(const half8*)(bufp_ + kb_ * 512);                     \
            tac = __builtin_amdgcn_mfma_f32_16x16x32_f16(afr[(KH) * 8 + kb_], bf, tac, 0, 0, 0); \
        }                                                                      \
        __builtin_amdgcn_s_setprio(0);                                         \
        if ((KH) == 1) {                                                       \
            float qv = qbs[cc_ * 16 + l15];                                    \
            float vv = vsh[cc_ * 16 + l15];                                    \
            _Pragma("unroll")                                                  \
            for (int j_ = 0; j_ < 4; j_++)                                     \
                S[j_] += ftanh(tac[j_] + qv) * vv;                             \
        }                                                                      \
    }

    for (int q = 0; q < 31; q++) {
        PHASE_BODY(2 * q,     "2", true, 0)
        PHASE_BODY(2 * q + 1, "2", true, 1)
    }
    PHASE_BODY(62, "2", false, 0)
    PHASE_BODY(63, "0", false, 1)
#undef PHASE_BODY

    // ---- logits: reduce over l15; row = w*16 + l4*4 + j ----
    #pragma unroll
    for (int j = 0; j < 4; j++) {
        float s = S[j];
        s += __shfl_xor(s, 1, 64);
        s += __shfl_xor(s, 2, 64);
        s += __shfl_xor(s, 4, 64);
        s += __shfl_xor(s, 8, 64);
        if (l15 == 0) {
            logits[m_base + w * 16 + l4 * 4 + j] = s;
            lsh[w * 16 + l4 * 4 + j] = s;
        }
    }
    __syncthreads();   // lsh complete; all waves past Wb reads (ews-alias safe)

    // ---- block-local softmax stats over the 64 rows ----
    float lv = lsh[lane];
    float mb = lv;
    mb = fmaxf(mb, __shfl_xor(mb, 1, 64));
    mb = fmaxf(mb, __shfl_xor(mb, 2, 64));
    mb = fmaxf(mb, __shfl_xor(mb, 4, 64));
    mb = fmaxf(mb, __shfl_xor(mb, 8, 64));
    mb = fmaxf(mb, __shfl_xor(mb, 16, 64));
    mb = fmaxf(mb, __shfl_xor(mb, 32, 64));
    float eb = __expf(lv - mb);
    float sb = eb;
    sb += __shfl_xor(sb, 1, 64);
    sb += __shfl_xor(sb, 2, 64);
    sb += __shfl_xor(sb, 4, 64);
    sb += __shfl_xor(sb, 8, 64);
    sb += __shfl_xor(sb, 16, 64);
    sb += __shfl_xor(sb, 32, 64);

    // ---- partial e_t from afr: e_blk[h] = sum_rows exp(l-mb) * x16[row][h] ----
    float coef = __expf(lsh[w * 16 + l15] - mb);
    float* ews = (float*)Wb;           // reuse 8 KB of Wb as [4][512] scratch
    #pragma unroll
    for (int kb = 0; kb < 16; kb++) {
        float ep[8];
        half8 x = afr[kb];
        #pragma unroll
        for (int e2 = 0; e2 < 8; e2++) ep[e2] = coef * (float)x[e2];
        #pragma unroll
        for (int e2 = 0; e2 < 8; e2++) {
            ep[e2] += __shfl_xor(ep[e2], 1, 64);
            ep[e2] += __shfl_xor(ep[e2], 2, 64);
            ep[e2] += __shfl_xor(ep[e2], 4, 64);
            ep[e2] += __shfl_xor(ep[e2], 8, 64);
        }
        if (l15 == 0) {
            #pragma unroll
            for (int e2 = 0; e2 < 8; e2++)
                ews[w * 512 + kb * 32 + l4 * 8 + e2] = ep[e2];
        }
    }
    __syncthreads();
    float v0 = ews[t] + ews[512 + t] + ews[1024 + t] + ews[1536 + t];
    float v1 = ews[256 + t] + ews[768 + t] + ews[1280 + t] + ews[1792 + t];
    eparts[(size_t)bx * 512 + t] = v0;
    eparts[(size_t)bx * 512 + 256 + t] = v1;
    if (t == 0) { ms[bx * 2] = mb; ms[bx * 2 + 1] = sb; }
}

// K3: combine 4 block-partials per b (exact flash-combine) -> alpha + e_t.
__global__ __launch_bounds__(256) void k_comb(const float* __restrict__ logits,
                                              const float* __restrict__ eparts,
                                              const float* __restrict__ ms,
                                              float* __restrict__ out) {
    int b = blockIdx.x, t = threadIdx.x;
    float m0 = ms[(4 * b + 0) * 2], s0 = ms[(4 * b + 0) * 2 + 1];
    float m1 = ms[(4 * b + 1) * 2], s1 = ms[(4 * b + 1) * 2 + 1];
    float m2 = ms[(4 * b + 2) * 2], s2 = ms[(4 * b + 2) * 2 + 1];
    float m3 = ms[(4 * b + 3) * 2], s3 = ms[(4 * b + 3) * 2 + 1];
    float m = fmaxf(fmaxf(m0, m1), fmaxf(m2, m3));
    float w0 = __expf(m0 - m), w1 = __expf(m1 - m);
    float w2 = __expf(m2 - m), w3 = __expf(m3 - m);
    float Sb = w0 * s0 + w1 * s1 + w2 * s2 + w3 * s3;
    float l = logits[b * 256 + t];
    out[BDIM * HDIM + b * 256 + t] = __expf(l - m) / Sb;   // alpha
    const float* ep = eparts + (size_t)(4 * b) * 512;
    float a0 = w0 * ep[t] + w1 * ep[512 + t] + w2 * ep[1024 + t] + w3 * ep[1536 + t];
    float a1 = w0 * ep[256 + t] + w1 * ep[768 + t] + w2 * ep[1280 + t] + w3 * ep[1792 + t];
    out[b * 512 + t] = a0 / Sb;                            // e_t
    out[b * 512 + 256 + t] = a1 / Sb;
}

extern "C" void kernel_launch(void* const* d_in, const int* in_sizes, int n_in,
                              void* d_out, int out_size, void* d_ws, size_t ws_size,
                              hipStream_t stream) {
    const float* h_tilde = (const float*)d_in[0];
    const float* c_t     = (const float*)d_in[1];
    const float* hist    = (const float*)d_in[2];
    const float* Waq     = (const float*)d_in[3];
    const float* Wah     = (const float*)d_in[4];
    const float* ba      = (const float*)d_in[5];
    const float* v_t     = (const float*)d_in[6];
    float* out = (float*)d_out;

    char* ws = (char*)d_ws;
    float*    qb     = (float*)ws;                                // 2 MB
    _Float16* W16    = (_Float16*)(ws + (2u << 20));              // 512 KB
    float*    logits = (float*)(ws + (3u << 20));                 // 1 MB
    float*    eparts = (float*)(ws + (4u << 20));                 // 8 MB
    float*    ms     = (float*)(ws + (12u << 20));                // 32 KB

    k_prep<<<384, 256, 0, stream>>>(h_tilde, c_t, Waq, ba, Wah, qb, W16);
    k_logits<<<4096, 256, 0, stream>>>(hist, qb, W16, v_t, logits, eparts, ms);
    k_comb<<<1024, 256, 0, stream>>>(logits, eparts, ms, out);
}

// Round 22
// 334.908 us; speedup vs baseline: 1.3245x; 1.0445x over previous
//
#include <hip/hip_runtime.h>
#include <hip/hip_bf16.h>

#define HDIM 512
#define BDIM 1024
#define DDIM 256
#define MTOT (BDIM * DDIM)

typedef _Float16 half8 __attribute__((ext_vector_type(8)));
typedef float f32x4 __attribute__((ext_vector_type(4)));

__device__ __forceinline__ float ftanh(float x) {
    float e = __expf(2.0f * x);
    float d = e + 1.0f;
    float r;
    asm("v_rcp_f32 %0, %1" : "=v"(r) : "v"(d));
    return 1.0f - 2.0f * r;
}

__device__ __forceinline__ void gl_lds16(const _Float16* src, _Float16* dst) {
    __builtin_amdgcn_global_load_lds((const __attribute__((address_space(1))) void*)src,
                                     (__attribute__((address_space(3))) void*)dst,
                                     16, 0, 0);
}

// K0 (merged): blocks 0..255 = qproj (16 b x 128 g tiles), 256..383 = convert.
// W16 PHASE-major: 64 phases of 4096 halves (16 cols x 256 k). Within phase
// p=(c,kh): granule kb*64 + kp*16 + g holds Wah[c*16+g][kh*256 + kb*32 + kp*8].
// B-frag for lane l = granule kb*64 + l -> 1024 consecutive bytes per wave
// (measured 0 bank conflicts).
__global__ __launch_bounds__(256) void k_prep(const float* __restrict__ h_tilde,
                                              const float* __restrict__ c_t,
                                              const float* __restrict__ Waq,
                                              const float* __restrict__ ba,
                                              const float* __restrict__ Wah,
                                              float* __restrict__ qb,
                                              _Float16* __restrict__ W16) {
    __shared__ float qs[16][1024];
    int t = threadIdx.x;
    if (blockIdx.x >= 256) {
        int n = (blockIdx.x - 256) * 256 + t;     // granule id, 32768 total
        int p = n >> 9, r = n & 511;
        int kb = r >> 6, kp = (r >> 4) & 3, g = r & 15;
        int c = p >> 1, kh = p & 1;
        const float* src = Wah + (size_t)(c * 16 + g) * 512 + kh * 256 + kb * 32 + kp * 8;
        float4 v0 = *(const float4*)src;
        float4 v1 = *(const float4*)(src + 4);
        half8 h;
        h[0] = (_Float16)v0.x; h[1] = (_Float16)v0.y; h[2] = (_Float16)v0.z; h[3] = (_Float16)v0.w;
        h[4] = (_Float16)v1.x; h[5] = (_Float16)v1.y; h[6] = (_Float16)v1.z; h[7] = (_Float16)v1.w;
        *(half8*)&W16[(size_t)n * 8] = h;
        return;
    }
    // ---- qproj: block = 16 b x 128 g ----
    int bt = blockIdx.x >> 2, gq = blockIdx.x & 3;
    int b0 = bt * 16;
    #pragma unroll
    for (int i = 0; i < 16; i++) {
        int idx = t + i * 256;
        int row = idx >> 8, k = (idx & 255) * 4;
        float4 v;
        if (k < 512) v = *(const float4*)&h_tilde[(b0 + row) * 512 + k];
        else         v = *(const float4*)&c_t[(b0 + row) * 512 + k - 512];
        *(float4*)&qs[row][k] = v;
    }
    __syncthreads();
    int g = gq * 128 + (t & 127);
    int bh = t >> 7;
    float acc[8] = {0.f, 0.f, 0.f, 0.f, 0.f, 0.f, 0.f, 0.f};
    const float4* wp = (const float4*)&Waq[(size_t)g * 1024];
    #pragma unroll 2
    for (int k4 = 0; k4 < 256; k4++) {
        float4 wv = wp[k4];
        #pragma unroll
        for (int j = 0; j < 8; j++) {
            float4 q = *(const float4*)&qs[bh * 8 + j][k4 * 4];
            acc[j] += q.x * wv.x + q.y * wv.y + q.z * wv.z + q.w * wv.w;
        }
    }
    float bav = ba[g];
    #pragma unroll
    for (int j = 0; j < 8; j++)
        qb[(b0 + bh * 8 + j) * 512 + g] = acc[j] + bav;
}

// K2: R14/R21 structure with prefetch DEPTH 3 (was 2): 64 rows x full N,
// 4 waves, afr[16] (64 AGPR, static indices), 4 blocks/CU, fused flash
// partial softmax + partial e_t. 4-buffer ring; body(p): vmcnt(4) [phase p
// complete; p+1,p+2 in flight] -> s_barrier -> issue p+3 (into buffer
// (p-1)&3, readers past the barrier) -> 8 ds_read + 8 MFMA -> fold on odd
// phase. Literal KH=0/1 keeps afr[] indices compile-time (rule #20).
__global__ __launch_bounds__(256, 4) void k_logits(const float* __restrict__ hist,
                                                   const float* __restrict__ qb,
                                                   const _Float16* __restrict__ W16,
                                                   const float* __restrict__ v_t,
                                                   float* __restrict__ logits,
                                                   float* __restrict__ eparts,
                                                   float* __restrict__ ms) {
    __shared__ _Float16 Wb[4][4096];   // 8 KB each; reused as e_t scratch after loop
    __shared__ float qbs[512];
    __shared__ float vsh[512];
    __shared__ float lsh[64];

    int t = threadIdx.x;
    int w = t >> 6, lane = t & 63, l15 = lane & 15, l4 = lane >> 4;
    int bx = blockIdx.x;
    size_t m_base = (size_t)bx * 64;
    int b = bx >> 2;
    int offp = ((bx >> 3) & 3) * 16;   // EVEN stagger -> kh parity preserved

    qbs[t] = qb[b * 512 + t];
    qbs[t + 256] = qb[b * 512 + 256 + t];
    vsh[t] = v_t[t];
    vsh[t + 256] = v_t[256 + t];

    // prologue: issue DMA for phases 0,1,2 (2 ops each per wave; 6 in flight)
    #pragma unroll
    for (int pp = 0; pp < 3; pp++) {
        const _Float16* wc = W16 + (size_t)((pp + offp) & 63) * 4096;
        #pragma unroll
        for (int sg = 0; sg < 2; sg++)
            gl_lds16(wc + ((size_t)(w * 2 + sg) * 64 + lane) * 8,
                     &Wb[pp][(w * 2 + sg) * 512]);
    }

    // X-load, depth-4 ring (static slots): afr[kb] = X[w*16+l15][kb*32+l4*8..+8]
    half8 afr[16];
    const float* xb = hist + (m_base + w * 16 + l15) * 512 + l4 * 8;
    {
        float4 xr0[4], xr1[4];
        #pragma unroll
        for (int u = 0; u < 4; u++) {
            xr0[u] = *(const float4*)(xb + u * 32);
            xr1[u] = *(const float4*)(xb + u * 32 + 4);
        }
        #pragma unroll
        for (int kb = 0; kb < 16; kb++) {
            const int slot = kb & 3;
            float4 v0 = xr0[slot];
            float4 v1 = xr1[slot];
            if (kb + 4 < 16) {
                xr0[slot] = *(const float4*)(xb + (kb + 4) * 32);
                xr1[slot] = *(const float4*)(xb + (kb + 4) * 32 + 4);
            }
            half8 h;
            h[0] = (_Float16)v0.x; h[1] = (_Float16)v0.y; h[2] = (_Float16)v0.z; h[3] = (_Float16)v0.w;
            h[4] = (_Float16)v1.x; h[5] = (_Float16)v1.y; h[6] = (_Float16)v1.z; h[7] = (_Float16)v1.w;
            afr[kb] = h;
        }
    }

    float S[4] = {0.f, 0.f, 0.f, 0.f};
    f32x4 tac = (f32x4){0.f, 0.f, 0.f, 0.f};

    asm volatile("s_waitcnt lgkmcnt(0)" ::: "memory");  // own qbs/vsh ds_writes

    // KH is a LITERAL (0/1) -> afr index static. p_ runtime: address math only.
#define PHASE_BODY(P, VMS, ISSUE, KH)                                          \
    {                                                                          \
        const int p_ = (P);                                                    \
        asm volatile("s_waitcnt vmcnt(" VMS ")" ::: "memory");                 \
        __builtin_amdgcn_s_barrier();                                          \
        if (ISSUE) {                                                           \
            const _Float16* wc_ = W16 + (size_t)((p_ + 3 + offp) & 63) * 4096; \
            _Float16* wd_ = Wb[(p_ + 3) & 3];                                  \
            _Pragma("unroll")                                                  \
            for (int sg_ = 0; sg_ < 2; sg_++)                                  \
                gl_lds16(wc_ + ((size_t)(w * 2 + sg_) * 64 + lane) * 8,        \
                         &wd_[(w * 2 + sg_) * 512]);                           \
        }                                                                      \
        const int cc_ = ((p_ + offp) & 63) >> 1;                               \
        const _Float16* bufp_ = &Wb[p_ & 3][lane * 8];                         \
        if ((KH) == 0) tac = (f32x4){0.f, 0.f, 0.f, 0.f};                      \
        __builtin_amdgcn_s_setprio(1);                                         \
        _Pragma("unroll")                                                      \
        for (int kb_ = 0; kb_ < 8; kb_++) {                                    \
            half8 bf = *(const half8*)(bufp_ + kb_ * 512);                     \
            tac = __builtin_amdgcn_mfma_f32_16x16x32_f16(afr[(KH) * 8 + kb_], bf, tac, 0, 0, 0); \
        }                                                                      \
        __builtin_amdgcn_s_setprio(0);                                         \
        if ((KH) == 1) {                                                       \
            float qv = qbs[cc_ * 16 + l15];                                    \
            float vv = vsh[cc_ * 16 + l15];                                    \
            _Pragma("unroll")                                                  \
            for (int j_ = 0; j_ < 4; j_++)                                     \
                S[j_] += ftanh(tac[j_] + qv) * vv;                             \
        }                                                                      \
    }

    for (int q = 0; q < 30; q++) {
        PHASE_BODY(2 * q,     "4", true, 0)
        PHASE_BODY(2 * q + 1, "4", true, 1)
    }
    PHASE_BODY(60, "4", true,  0)   // issues phase 63 (last)
    PHASE_BODY(61, "4", false, 1)
    PHASE_BODY(62, "2", false, 0)
    PHASE_BODY(63, "0", false, 1)
#undef PHASE_BODY

    // ---- logits: reduce over l15; row = w*16 + l4*4 + j ----
    #pragma unroll
    for (int j = 0; j < 4; j++) {
        float s = S[j];
        s += __shfl_xor(s, 1, 64);
        s += __shfl_xor(s, 2, 64);
        s += __shfl_xor(s, 4, 64);
        s += __shfl_xor(s, 8, 64);
        if (l15 == 0) {
            logits[m_base + w * 16 + l4 * 4 + j] = s;
            lsh[w * 16 + l4 * 4 + j] = s;
        }
    }
    __syncthreads();   // lsh complete; all waves past Wb reads (ews-alias safe)

    // ---- block-local softmax stats over the 64 rows ----
    float lv = lsh[lane];
    float mb = lv;
    mb = fmaxf(mb, __shfl_xor(mb, 1, 64));
    mb = fmaxf(mb, __shfl_xor(mb, 2, 64));
    mb = fmaxf(mb, __shfl_xor(mb, 4, 64));
    mb = fmaxf(mb, __shfl_xor(mb, 8, 64));
    mb = fmaxf(mb, __shfl_xor(mb, 16, 64));
    mb = fmaxf(mb, __shfl_xor(mb, 32, 64));
    float eb = __expf(lv - mb);
    float sb = eb;
    sb += __shfl_xor(sb, 1, 64);
    sb += __shfl_xor(sb, 2, 64);
    sb += __shfl_xor(sb, 4, 64);
    sb += __shfl_xor(sb, 8, 64);
    sb += __shfl_xor(sb, 16, 64);
    sb += __shfl_xor(sb, 32, 64);

    // ---- partial e_t from afr: e_blk[h] = sum_rows exp(l-mb) * x16[row][h] ----
    float coef = __expf(lsh[w * 16 + l15] - mb);
    float* ews = (float*)Wb;           // reuse 8 KB of Wb as [4][512] scratch
    #pragma unroll
    for (int kb = 0; kb < 16; kb++) {
        float ep[8];
        half8 x = afr[kb];
        #pragma unroll
        for (int e2 = 0; e2 < 8; e2++) ep[e2] = coef * (float)x[e2];
        #pragma unroll
        for (int e2 = 0; e2 < 8; e2++) {
            ep[e2] += __shfl_xor(ep[e2], 1, 64);
            ep[e2] += __shfl_xor(ep[e2], 2, 64);
            ep[e2] += __shfl_xor(ep[e2], 4, 64);
            ep[e2] += __shfl_xor(ep[e2], 8, 64);
        }
        if (l15 == 0) {
            #pragma unroll
            for (int e2 = 0; e2 < 8; e2++)
                ews[w * 512 + kb * 32 + l4 * 8 + e2] = ep[e2];
        }
    }
    __syncthreads();
    float v0 = ews[t] + ews[512 + t] + ews[1024 + t] + ews[1536 + t];
    float v1 = ews[256 + t] + ews[768 + t] + ews[1280 + t] + ews[1792 + t];
    eparts[(size_t)bx * 512 + t] = v0;
    eparts[(size_t)bx * 512 + 256 + t] = v1;
    if (t == 0) { ms[bx * 2] = mb; ms[bx * 2 + 1] = sb; }
}

// K3: combine 4 block-partials per b (exact flash-combine) -> alpha + e_t.
__global__ __launch_bounds__(256) void k_comb(const float* __restrict__ logits,
                                              const float* __restrict__ eparts,
                                              const float* __restrict__ ms,
                                              float* __restrict__ out) {
    int b = blockIdx.x, t = threadIdx.x;
    float m0 = ms[(4 * b + 0) * 2], s0 = ms[(4 * b + 0) * 2 + 1];
    float m1 = ms[(4 * b + 1) * 2], s1 = ms[(4 * b + 1) * 2 + 1];
    float m2 = ms[(4 * b + 2) * 2], s2 = ms[(4 * b + 2) * 2 + 1];
    float m3 = ms[(4 * b + 3) * 2], s3 = ms[(4 * b + 3) * 2 + 1];
    float m = fmaxf(fmaxf(m0, m1), fmaxf(m2, m3));
    float w0 = __expf(m0 - m), w1 = __expf(m1 - m);
    float w2 = __expf(m2 - m), w3 = __expf(m3 - m);
    float Sb = w0 * s0 + w1 * s1 + w2 * s2 + w3 * s3;
    float l = logits[b * 256 + t];
    out[BDIM * HDIM + b * 256 + t] = __expf(l - m) / Sb;   // alpha
    const float* ep = eparts + (size_t)(4 * b) * 512;
    float a0 = w0 * ep[t] + w1 * ep[512 + t] + w2 * ep[1024 + t] + w3 * ep[1536 + t];
    float a1 = w0 * ep[256 + t] + w1 * ep[768 + t] + w2 * ep[1280 + t] + w3 * ep[1792 + t];
    out[b * 512 + t] = a0 / Sb;                            // e_t
    out[b * 512 + 256 + t] = a1 / Sb;
}

extern "C" void kernel_launch(void* const* d_in, const int* in_sizes, int n_in,
                              void* d_out, int out_size, void* d_ws, size_t ws_size,
                              hipStream_t stream) {
    const float* h_tilde = (const float*)d_in[0];
    const float* c_t     = (const float*)d_in[1];
    const float* hist    = (const float*)d_in[2];
    const float* Waq     = (const float*)d_in[3];
    const float* Wah     = (const float*)d_in[4];
    const float* ba      = (const float*)d_in[5];
    const float* v_t     = (const float*)d_in[6];
    float* out = (float*)d_out;

    char* ws = (char*)d_ws;
    float*    qb     = (float*)ws;                                // 2 MB
    _Float16* W16    = (_Float16*)(ws + (2u << 20));              // 512 KB
    float*    logits = (float*)(ws + (3u << 20));                 // 1 MB
    float*    eparts = (float*)(ws + (4u << 20));                 // 8 MB
    float*    ms     = (float*)(ws + (12u << 20));                // 32 KB

    k_prep<<<384, 256, 0, stream>>>(h_tilde, c_t, Waq, ba, Wah, qb, W16);
    k_logits<<<4096, 256, 0, stream>>>(hist, qb, W16, v_t, logits, eparts, ms);
    k_comb<<<1024, 256, 0, stream>>>(logits, eparts, ms, out);
}